// Round 1
// baseline (1233.181 us; speedup 1.0000x reference)
//
#include <hip/hip_runtime.h>
#include <math.h>

// Problem constants
#define B_      32
#define C_IN    64
#define H_      4096
#define F_      8
#define OUT_CH  9          // F+1
#define KW      5          // F/2+1
#define BH      (B_ * H_)  // 131072 independent (b,h) problems
#define LOC_N   (BH * F_)  // 1048576 floats of loc output
#define NSWEEP  6
#define MIN_VEC 0.001f

// Tournament (round-robin) parallel-Jacobi ordering: 7 rounds x 4 disjoint
// pairs covers all 28 (p,q) pairs, p<q.
__device__ const int PAIRS[7][4][2] = {
  {{0,7},{1,6},{2,5},{3,4}},
  {{0,6},{5,7},{1,4},{2,3}},
  {{0,5},{4,6},{3,7},{1,2}},
  {{0,4},{3,5},{2,6},{1,7}},
  {{0,3},{2,4},{1,5},{6,7}},
  {{0,2},{1,3},{4,7},{5,6}},
  {{0,1},{2,7},{3,6},{4,5}},
};

#define SYM(i,j) (((i) < (j)) ? A[i][j] : A[j][i])

__device__ __forceinline__ float softplus_f(float v) {
    return fmaxf(v, 0.0f) + __logf(1.0f + __expf(-fabsf(v)));
}

// 2 threads per (b,h) problem. Block = 256 threads = 128 problems.
// waves 0-1: channel half 0; waves 2-3: channel half 1 (wave-uniform -> no
// divergence, weights stay s_load). Partial conv sums combined via LDS.
// Both halves run the Jacobi redundantly (issue slots were idle anyway);
// output writes are split (half0: loc + PD rows 0-3, half1: PD rows 4-7).
__global__ __launch_bounds__(256, 4)
void mgauss_fused(const float* __restrict__ x,
                  const float* __restrict__ w_n,
                  const float* __restrict__ b_n,
                  const float* __restrict__ w_p,
                  const float* __restrict__ b_p,
                  float* __restrict__ out)
{
    __shared__ float xsh[128][45];   // 44 partials + pad (stride 45: bank-conflict-free)

    const int tid  = threadIdx.x;
    const int wv   = tid >> 6;            // wave in block: 0..3
    const int lane = tid & 63;
    const int halfsel = wv >> 1;          // 0 for waves 0-1, 1 for waves 2-3 (wave-uniform)
    const int pl   = ((wv & 1) << 6) | lane;      // local problem 0..127
    const int t    = blockIdx.x * 128 + pl;       // global problem id
    const int b    = t >> 12;             // /4096
    const int h    = t & 4095;

    // x[b, c, h, w] at ((b*64 + c)*4096 + h)*8 + w ; per-c stride = 32768 floats
    const float* xp = x + ((size_t)b * C_IN * H_ + h) * F_;
    // channel base for this half; readfirstlane proves wave-uniformity to the
    // compiler so weight loads become s_load
    const int c0 = __builtin_amdgcn_readfirstlane(halfsel << 5);

    // acc[0..7] = loc partial, acc[8 + o*4 + wo] = p-conv partial
    float acc[44];
    #pragma unroll
    for (int k = 0; k < 44; ++k) acc[k] = 0.0f;

    #pragma unroll 4
    for (int c = 0; c < 32; ++c) {
        const int cc = c0 + c;
        const float4 x0 = *(const float4*)(xp + (size_t)cc * (H_ * F_));
        const float4 x1 = *(const float4*)(xp + (size_t)cc * (H_ * F_) + 4);
        const float xa[F_] = {x0.x, x0.y, x0.z, x0.w, x1.x, x1.y, x1.z, x1.w};

        const float wn = w_n[cc];   // uniform -> s_load
        #pragma unroll
        for (int w = 0; w < F_; ++w) acc[w] = fmaf(xa[w], wn, acc[w]);

        #pragma unroll
        for (int o = 0; o < OUT_CH; ++o) {
            #pragma unroll
            for (int k = 0; k < KW; ++k) {
                const float wvp = w_p[(o * C_IN + cc) * KW + k];  // uniform -> s_load
                #pragma unroll
                for (int wo = 0; wo < 4; ++wo)
                    acc[8 + o * 4 + wo] = fmaf(xa[wo + k], wvp, acc[8 + o * 4 + wo]);
            }
        }
    }

    // ---- combine the two channel-halves through LDS (asymmetric, 2 barriers,
    //      single 23KB buffer so 4 blocks/CU still fit)
    if (halfsel) {
        #pragma unroll
        for (int k = 0; k < 44; ++k) xsh[pl][k] = acc[k];
    }
    __syncthreads();
    if (!halfsel) {
        #pragma unroll
        for (int k = 0; k < 44; ++k) acc[k] += xsh[pl][k];
        #pragma unroll
        for (int k = 8; k < 44; ++k) xsh[pl][k] = acc[k];   // half1 only needs sigma part
    }
    __syncthreads();
    if (halfsel) {
        #pragma unroll
        for (int k = 8; k < 44; ++k) acc[k] = xsh[pl][k];
    }

    // ---- loc output (half 0 only): softplus(conv1x1 + b_n), layout [B,1,H,8]
    if (!halfsel) {
        const float bn = b_n[0];
        float lv[F_];
        #pragma unroll
        for (int w = 0; w < F_; ++w) lv[w] = softplus_f(acc[w] + bn);
        float* lo = out + (size_t)t * F_;
        *(float4*)(lo)     = make_float4(lv[0], lv[1], lv[2], lv[3]);
        *(float4*)(lo + 4) = make_float4(lv[4], lv[5], lv[6], lv[7]);
    }

    // ---- build symmetric A (upper triangle only) from sigma
    float A[F_][F_];
    {
        float sig[36];
        #pragma unroll
        for (int o = 0; o < OUT_CH; ++o) {
            const float bp = b_p[o];
            #pragma unroll
            for (int wo = 0; wo < 4; ++wo)
                sig[o * 4 + wo] = softplus_f(acc[8 + o * 4 + wo] + bp);
        }
        int k = 0;
        #pragma unroll
        for (int i = 0; i < F_; ++i)
            #pragma unroll
            for (int j = i; j < F_; ++j) {
                A[i][j] = sig[k];
                ++k;
            }
    }

    float V[F_][F_];
    #pragma unroll
    for (int i = 0; i < F_; ++i)
        #pragma unroll
        for (int j = 0; j < F_; ++j)
            V[i][j] = (i == j) ? 1.0f : 0.0f;

    // ---- parallel-ordering Jacobi; angle setup uses raw v_rcp/v_sqrt/v_rsq
    //      (1-2 ulp, fine vs 1.5e-2 tolerance; saves ~10 instr per divide)
    for (int sweep = 0; sweep < NSWEEP; ++sweep) {
        #pragma unroll
        for (int r = 0; r < 7; ++r) {
            float cs[4], sn[4], tv[4];
            #pragma unroll
            for (int j = 0; j < 4; ++j) {
                const int p = PAIRS[r][j][0], q = PAIRS[r][j][1];
                const float apq = A[p][q];
                const float app = A[p][p];
                const float aqq = A[q][q];
                const float th = (aqq - app) * 0.5f * __builtin_amdgcn_rcpf(apq);
                float tt = __builtin_amdgcn_rcpf(fabsf(th) +
                              __builtin_amdgcn_sqrtf(fmaf(th, th, 1.0f)));
                tt = (th < 0.0f) ? -tt : tt;
                tt = (apq == 0.0f) ? 0.0f : tt;   // kills NaN from 0 * inf
                const float cc = __builtin_amdgcn_rsqf(fmaf(tt, tt, 1.0f));
                cs[j] = cc; sn[j] = tt * cc; tv[j] = tt;
            }
            // A updates: disjoint pairs -> sequential application == R A R^T
            #pragma unroll
            for (int j = 0; j < 4; ++j) {
                const int p = PAIRS[r][j][0], q = PAIRS[r][j][1];
                const float cc = cs[j], ss = sn[j], tt = tv[j];
                const float apq = A[p][q];
                A[p][p] = fmaf(-tt, apq, A[p][p]);
                A[q][q] = fmaf( tt, apq, A[q][q]);
                A[p][q] = 0.0f;
                #pragma unroll
                for (int i = 0; i < F_; ++i) {
                    if (i == p || i == q) continue;
                    const float aip = SYM(i, p);
                    const float aiq = SYM(i, q);
                    SYM(i, p) = fmaf(-ss, aiq, cc * aip);
                    SYM(i, q) = fmaf( ss, aip, cc * aiq);
                }
            }
            // V updates: columns p,q per pair, fully independent across pairs
            #pragma unroll
            for (int j = 0; j < 4; ++j) {
                const int p = PAIRS[r][j][0], q = PAIRS[r][j][1];
                const float cc = cs[j], ss = sn[j];
                #pragma unroll
                for (int i = 0; i < F_; ++i) {
                    const float u = V[i][p], v = V[i][q];
                    V[i][p] = fmaf(-ss, v, cc * u);
                    V[i][q] = fmaf( ss, u, cc * v);
                }
            }
        }
    }

    // ---- reconstruct PD = V * max(diag(A), MIN_VEC) * V^T (exactly symmetric)
    float lam[F_];
    #pragma unroll
    for (int k = 0; k < F_; ++k) lam[k] = fmaxf(A[k][k], MIN_VEC);

    float W[F_][F_];
    #pragma unroll
    for (int i = 0; i < F_; ++i)
        #pragma unroll
        for (int k = 0; k < F_; ++k)
            W[i][k] = V[i][k] * lam[k];

    float PD[F_][F_];
    #pragma unroll
    for (int i = 0; i < F_; ++i) {
        #pragma unroll
        for (int j = i; j < F_; ++j) {
            float fa = 0.0f;
            #pragma unroll
            for (int k = 0; k < F_; ++k)
                fa = fmaf(W[i][k], V[j][k], fa);
            PD[i][j] = fa;
            PD[j][i] = fa;
        }
    }

    // ---- split PD writes: half0 rows 0-3, half1 rows 4-7 (all indices
    //      compile-time so PD stays in registers)
    float* po = out + LOC_N + (size_t)t * (F_ * F_);
    if (!halfsel) {
        #pragma unroll
        for (int i = 0; i < 4; ++i) {
            *(float4*)(po + i * F_)     = make_float4(PD[i][0], PD[i][1], PD[i][2], PD[i][3]);
            *(float4*)(po + i * F_ + 4) = make_float4(PD[i][4], PD[i][5], PD[i][6], PD[i][7]);
        }
    } else {
        #pragma unroll
        for (int i = 4; i < 8; ++i) {
            *(float4*)(po + i * F_)     = make_float4(PD[i][0], PD[i][1], PD[i][2], PD[i][3]);
            *(float4*)(po + i * F_ + 4) = make_float4(PD[i][4], PD[i][5], PD[i][6], PD[i][7]);
        }
    }
}

extern "C" void kernel_launch(void* const* d_in, const int* in_sizes, int n_in,
                              void* d_out, int out_size, void* d_ws, size_t ws_size,
                              hipStream_t stream) {
    const float* x   = (const float*)d_in[0];
    const float* w_n = (const float*)d_in[1];
    const float* b_n = (const float*)d_in[2];
    const float* w_p = (const float*)d_in[3];
    const float* b_p = (const float*)d_in[4];
    float* out = (float*)d_out;

    dim3 grid(BH / 128);   // 1024 blocks, 2 threads per problem
    dim3 block(256);
    hipLaunchKernelGGL(mgauss_fused, grid, block, 0, stream,
                       x, w_n, b_n, w_p, b_p, out);
}

// Round 2
// 1147.810 us; speedup vs baseline: 1.0744x; 1.0744x over previous
//
#include <hip/hip_runtime.h>
#include <math.h>

// Problem constants
#define B_      32
#define C_IN    64
#define H_      4096
#define F_      8
#define OUT_CH  9          // F+1
#define KW      5          // F/2+1
#define BH      (B_ * H_)  // 131072 independent (b,h) problems
#define LOC_N   (BH * F_)  // 1048576 floats of loc output
#define NSWEEP  6
#define MIN_VEC 0.001f
#define LSTR    65         // LDS row stride (floats); 65 % 32 == 1 -> conflict-free

// Tournament (round-robin) parallel-Jacobi ordering: 7 rounds x 4 disjoint
// pairs covers all 28 (p,q) pairs, p<q.
__device__ const int PAIRS[7][4][2] = {
  {{0,7},{1,6},{2,5},{3,4}},
  {{0,6},{5,7},{1,4},{2,3}},
  {{0,5},{4,6},{3,7},{1,2}},
  {{0,4},{3,5},{2,6},{1,7}},
  {{0,3},{2,4},{1,5},{6,7}},
  {{0,2},{1,3},{4,7},{5,6}},
  {{0,1},{2,7},{3,6},{4,5}},
};

#define SYM(i,j) (((i) < (j)) ? A[i][j] : A[j][i])

__device__ __forceinline__ float softplus_f(float v) {
    return fmaxf(v, 0.0f) + __logf(1.0f + __expf(-fabsf(v)));
}

// 2 threads per (b,h) problem. Block = 256 threads = 128 problems.
// waves 0-1: channel half 0; waves 2-3: channel half 1 (wave-uniform).
// Conv partials combined via LDS. A-Jacobi runs redundantly in both halves
// (identical data -> identical rotations); V is row-split: each half tracks
// only its 4 rows (column rotations never mix V rows). One LDS exchange of
// the V halves at the end lets each half reconstruct its 4 PD rows.
// waves_per_eu(4,4) pins the allocator to the 128-VGPR / 4-waves-per-SIMD
// tier (round-1 regression: launch_bounds(256,4) let the backend target 8
// waves/EU -> 64 VGPR -> 2.9 GB of scratch spill traffic).
__global__ __launch_bounds__(256)
__attribute__((amdgpu_waves_per_eu(4, 4)))
void mgauss_fused(const float* __restrict__ x,
                  const float* __restrict__ w_n,
                  const float* __restrict__ b_n,
                  const float* __restrict__ w_p,
                  const float* __restrict__ b_p,
                  float* __restrict__ out)
{
    __shared__ float xsh[128][LSTR];   // 33280 B; 4 blocks/CU -> 130 KB of 160 KB

    const int tid  = threadIdx.x;
    const int wv   = tid >> 6;            // wave in block: 0..3
    const int lane = tid & 63;
    const int halfsel = wv >> 1;          // 0 for waves 0-1, 1 for waves 2-3 (wave-uniform)
    const int pl   = ((wv & 1) << 6) | lane;      // local problem 0..127
    const int t    = blockIdx.x * 128 + pl;       // global problem id
    const int b    = t >> 12;             // /4096
    const int h    = t & 4095;

    // x[b, c, h, w] at ((b*64 + c)*4096 + h)*8 + w ; per-c stride = 32768 floats
    const float* xp = x + ((size_t)b * C_IN * H_ + h) * F_;
    // channel base for this half; readfirstlane proves wave-uniformity so
    // weight loads stay s_load
    const int c0 = __builtin_amdgcn_readfirstlane(halfsel << 5);

    // acc[0..7] = loc partial, acc[8 + o*4 + wo] = p-conv partial
    float acc[44];
    #pragma unroll
    for (int k = 0; k < 44; ++k) acc[k] = 0.0f;

    #pragma unroll 4
    for (int c = 0; c < 32; ++c) {
        const int cc = c0 + c;
        const float4 x0 = *(const float4*)(xp + (size_t)cc * (H_ * F_));
        const float4 x1 = *(const float4*)(xp + (size_t)cc * (H_ * F_) + 4);
        const float xa[F_] = {x0.x, x0.y, x0.z, x0.w, x1.x, x1.y, x1.z, x1.w};

        const float wn = w_n[cc];   // uniform -> s_load
        #pragma unroll
        for (int w = 0; w < F_; ++w) acc[w] = fmaf(xa[w], wn, acc[w]);

        #pragma unroll
        for (int o = 0; o < OUT_CH; ++o) {
            #pragma unroll
            for (int k = 0; k < KW; ++k) {
                const float wvp = w_p[(o * C_IN + cc) * KW + k];  // uniform -> s_load
                #pragma unroll
                for (int wo = 0; wo < 4; ++wo)
                    acc[8 + o * 4 + wo] = fmaf(xa[wo + k], wvp, acc[8 + o * 4 + wo]);
            }
        }
    }

    // ---- combine the two channel-halves through LDS (asymmetric, 2 barriers)
    if (halfsel) {
        #pragma unroll
        for (int k = 0; k < 44; ++k) xsh[pl][k] = acc[k];
    }
    __syncthreads();
    if (!halfsel) {
        #pragma unroll
        for (int k = 0; k < 44; ++k) acc[k] += xsh[pl][k];
        #pragma unroll
        for (int k = 8; k < 44; ++k) xsh[pl][k] = acc[k];   // half1 only needs sigma part
    }
    __syncthreads();
    if (halfsel) {
        #pragma unroll
        for (int k = 8; k < 44; ++k) acc[k] = xsh[pl][k];
    }

    // ---- loc output (half 0 only): softplus(conv1x1 + b_n), layout [B,1,H,8]
    if (!halfsel) {
        const float bn = b_n[0];
        float lv[F_];
        #pragma unroll
        for (int w = 0; w < F_; ++w) lv[w] = softplus_f(acc[w] + bn);
        float* lo = out + (size_t)t * F_;
        *(float4*)(lo)     = make_float4(lv[0], lv[1], lv[2], lv[3]);
        *(float4*)(lo + 4) = make_float4(lv[4], lv[5], lv[6], lv[7]);
    }

    // ---- build symmetric A (upper triangle only) from sigma
    float A[F_][F_];
    {
        float sig[36];
        #pragma unroll
        for (int o = 0; o < OUT_CH; ++o) {
            const float bp = b_p[o];
            #pragma unroll
            for (int wo = 0; wo < 4; ++wo)
                sig[o * 4 + wo] = softplus_f(acc[8 + o * 4 + wo] + bp);
        }
        int k = 0;
        #pragma unroll
        for (int i = 0; i < F_; ++i)
            #pragma unroll
            for (int j = i; j < F_; ++j) {
                A[i][j] = sig[k];
                ++k;
            }
    }

    // Row-split V: this half tracks rows [myBase, myBase+4) only.
    const int myBase = halfsel << 2;
    float Vh[4][F_];
    #pragma unroll
    for (int i = 0; i < 4; ++i)
        #pragma unroll
        for (int j = 0; j < F_; ++j)
            Vh[i][j] = (myBase + i == j) ? 1.0f : 0.0f;

    // ---- parallel-ordering Jacobi; angle setup uses raw v_rcp/v_sqrt/v_rsq
    //      (1-2 ulp, fine vs the harness tolerance)
    for (int sweep = 0; sweep < NSWEEP; ++sweep) {
        #pragma unroll
        for (int r = 0; r < 7; ++r) {
            float cs[4], sn[4], tv[4];
            #pragma unroll
            for (int j = 0; j < 4; ++j) {
                const int p = PAIRS[r][j][0], q = PAIRS[r][j][1];
                const float apq = A[p][q];
                const float app = A[p][p];
                const float aqq = A[q][q];
                const float th = (aqq - app) * 0.5f * __builtin_amdgcn_rcpf(apq);
                float tt = __builtin_amdgcn_rcpf(fabsf(th) +
                              __builtin_amdgcn_sqrtf(fmaf(th, th, 1.0f)));
                tt = (th < 0.0f) ? -tt : tt;
                tt = (apq == 0.0f) ? 0.0f : tt;   // kills NaN from 0 * inf
                const float cc = __builtin_amdgcn_rsqf(fmaf(tt, tt, 1.0f));
                cs[j] = cc; sn[j] = tt * cc; tv[j] = tt;
            }
            // A updates: disjoint pairs -> sequential application == R A R^T
            #pragma unroll
            for (int j = 0; j < 4; ++j) {
                const int p = PAIRS[r][j][0], q = PAIRS[r][j][1];
                const float cc = cs[j], ss = sn[j], tt = tv[j];
                const float apq = A[p][q];
                A[p][p] = fmaf(-tt, apq, A[p][p]);
                A[q][q] = fmaf( tt, apq, A[q][q]);
                A[p][q] = 0.0f;
                #pragma unroll
                for (int i = 0; i < F_; ++i) {
                    if (i == p || i == q) continue;
                    const float aip = SYM(i, p);
                    const float aiq = SYM(i, q);
                    SYM(i, p) = fmaf(-ss, aiq, cc * aip);
                    SYM(i, q) = fmaf( ss, aip, cc * aiq);
                }
            }
            // V updates: only our 4 rows (column rotations stay within a row)
            #pragma unroll
            for (int j = 0; j < 4; ++j) {
                const int p = PAIRS[r][j][0], q = PAIRS[r][j][1];
                const float cc = cs[j], ss = sn[j];
                #pragma unroll
                for (int i = 0; i < 4; ++i) {
                    const float u = Vh[i][p], v = Vh[i][q];
                    Vh[i][p] = fmaf(-ss, v, cc * u);
                    Vh[i][q] = fmaf( ss, u, cc * v);
                }
            }
        }
    }

    // ---- eigenvalues (identical in both halves: same A, same rotations)
    float lam[F_];
    #pragma unroll
    for (int k = 0; k < F_; ++k) lam[k] = fmaxf(A[k][k], MIN_VEC);

    // ---- exchange V halves through LDS (reuse xsh; row has 65 >= 64 floats)
    __syncthreads();   // guard: half1's sigma reads above must complete
    {
        const int moff = myBase << 3;          // halfsel*32
        #pragma unroll
        for (int i = 0; i < 4; ++i)
            #pragma unroll
            for (int j = 0; j < F_; ++j)
                xsh[pl][moff + (i << 3) + j] = Vh[i][j];
    }
    __syncthreads();
    float Vo[4][F_];
    {
        const int ooff = (myBase ^ 4) << 3;    // other half's 32 floats
        #pragma unroll
        for (int i = 0; i < 4; ++i)
            #pragma unroll
            for (int j = 0; j < F_; ++j)
                Vo[i][j] = xsh[pl][ooff + (i << 3) + j];
    }

    // ---- reconstruct our 4 rows of PD = V * max(diag(A),MIN_VEC) * V^T.
    // Both halves use the same lam and same k-order -> output exactly symmetric.
    float W[4][F_];
    #pragma unroll
    for (int i = 0; i < 4; ++i)
        #pragma unroll
        for (int k = 0; k < F_; ++k)
            W[i][k] = Vh[i][k] * lam[k];

    float* po = out + LOC_N + (size_t)t * (F_ * F_) + myBase * F_;
    #pragma unroll
    for (int r = 0; r < 4; ++r) {
        float pa[4], pb[4];
        #pragma unroll
        for (int s = 0; s < 4; ++s) {
            float a0 = 0.0f, b0 = 0.0f;
            #pragma unroll
            for (int k = 0; k < F_; ++k) {
                a0 = fmaf(W[r][k], Vh[s][k], a0);   // columns in our half
                b0 = fmaf(W[r][k], Vo[s][k], b0);   // columns in other half
            }
            pa[s] = a0; pb[s] = b0;
        }
        float* pr = po + r * F_;
        *(float4*)(pr + myBase)       = make_float4(pa[0], pa[1], pa[2], pa[3]);
        *(float4*)(pr + (myBase ^ 4)) = make_float4(pb[0], pb[1], pb[2], pb[3]);
    }
}

extern "C" void kernel_launch(void* const* d_in, const int* in_sizes, int n_in,
                              void* d_out, int out_size, void* d_ws, size_t ws_size,
                              hipStream_t stream) {
    const float* x   = (const float*)d_in[0];
    const float* w_n = (const float*)d_in[1];
    const float* b_n = (const float*)d_in[2];
    const float* w_p = (const float*)d_in[3];
    const float* b_p = (const float*)d_in[4];
    float* out = (float*)d_out;

    dim3 grid(BH / 128);   // 1024 blocks, 2 threads per problem
    dim3 block(256);
    hipLaunchKernelGGL(mgauss_fused, grid, block, 0, stream,
                       x, w_n, b_n, w_p, b_p, out);
}

// Round 3
// 460.892 us; speedup vs baseline: 2.6756x; 2.4904x over previous
//
#include <hip/hip_runtime.h>
#include <math.h>

// Problem constants
#define B_      32
#define C_IN    64
#define H_      4096
#define F_      8
#define OUT_CH  9          // F+1
#define KW      5          // F/2+1
#define BH      (B_ * H_)  // 131072 independent (b,h) problems
#define LOC_N   (BH * F_)  // 1048576 floats of loc output
#define NSWEEP  6
#define MIN_VEC 0.001f
#define LSTR    65         // LDS row stride (floats); 65 % 32 == 1 -> conflict-free

// Tournament (round-robin) parallel-Jacobi ordering: 7 rounds x 4 disjoint
// pairs covers all 28 (p,q) pairs, p<q.
__device__ const int PAIRS[7][4][2] = {
  {{0,7},{1,6},{2,5},{3,4}},
  {{0,6},{5,7},{1,4},{2,3}},
  {{0,5},{4,6},{3,7},{1,2}},
  {{0,4},{3,5},{2,6},{1,7}},
  {{0,3},{2,4},{1,5},{6,7}},
  {{0,2},{1,3},{4,7},{5,6}},
  {{0,1},{2,7},{3,6},{4,5}},
};

#define SYM(i,j) (((i) < (j)) ? A[i][j] : A[j][i])

__device__ __forceinline__ float softplus_f(float v) {
    return fmaxf(v, 0.0f) + __logf(1.0f + __expf(-fabsf(v)));
}

// 2 threads per (b,h) problem. Block = 256 threads = 128 problems.
// waves 0-1: channel half 0; waves 2-3: channel half 1 (wave-uniform).
// Conv partials combined via LDS. A-Jacobi runs redundantly in both halves
// (identical data -> identical rotations); V is row-split: each half tracks
// only its 4 rows (column rotations never mix V rows). One LDS exchange of
// the V halves at the end lets each half reconstruct its 4 PD rows.
//
// REGISTER BUDGET (session-measured): __launch_bounds__(256,2) -> 128 VGPR,
// no spill (round 0). (256,4) and amdgpu_waves_per_eu(4,4) both made the
// backend target the 8-waves/EU tier -> 64 VGPR -> ~2 GB scratch traffic
// (rounds 1-2). Keep (256,2); occupancy is then naturally VGPR-limited at
// 4 waves/SIMD and LDS-limited at 4 blocks/CU.
__global__ __launch_bounds__(256, 2)
void mgauss_fused(const float* __restrict__ x,
                  const float* __restrict__ w_n,
                  const float* __restrict__ b_n,
                  const float* __restrict__ w_p,
                  const float* __restrict__ b_p,
                  float* __restrict__ out)
{
    __shared__ float xsh[128][LSTR];   // 33280 B; 4 blocks/CU -> 130 KB of 160 KB

    const int tid  = threadIdx.x;
    const int wv   = tid >> 6;            // wave in block: 0..3
    const int lane = tid & 63;
    const int halfsel = wv >> 1;          // 0 for waves 0-1, 1 for waves 2-3 (wave-uniform)
    const int pl   = ((wv & 1) << 6) | lane;      // local problem 0..127
    const int t    = blockIdx.x * 128 + pl;       // global problem id
    const int b    = t >> 12;             // /4096
    const int h    = t & 4095;

    // x[b, c, h, w] at ((b*64 + c)*4096 + h)*8 + w ; per-c stride = 32768 floats
    const float* xp = x + ((size_t)b * C_IN * H_ + h) * F_;
    // channel base for this half; readfirstlane proves wave-uniformity so
    // weight loads stay s_load
    const int c0 = __builtin_amdgcn_readfirstlane(halfsel << 5);

    // acc[0..7] = loc partial, acc[8 + o*4 + wo] = p-conv partial
    float acc[44];
    #pragma unroll
    for (int k = 0; k < 44; ++k) acc[k] = 0.0f;

    #pragma unroll 4
    for (int c = 0; c < 32; ++c) {
        const int cc = c0 + c;
        const float4 x0 = *(const float4*)(xp + (size_t)cc * (H_ * F_));
        const float4 x1 = *(const float4*)(xp + (size_t)cc * (H_ * F_) + 4);
        const float xa[F_] = {x0.x, x0.y, x0.z, x0.w, x1.x, x1.y, x1.z, x1.w};

        const float wn = w_n[cc];   // uniform -> s_load
        #pragma unroll
        for (int w = 0; w < F_; ++w) acc[w] = fmaf(xa[w], wn, acc[w]);

        #pragma unroll
        for (int o = 0; o < OUT_CH; ++o) {
            #pragma unroll
            for (int k = 0; k < KW; ++k) {
                const float wvp = w_p[(o * C_IN + cc) * KW + k];  // uniform -> s_load
                #pragma unroll
                for (int wo = 0; wo < 4; ++wo)
                    acc[8 + o * 4 + wo] = fmaf(xa[wo + k], wvp, acc[8 + o * 4 + wo]);
            }
        }
    }

    // ---- combine the two channel-halves through LDS (asymmetric, 2 barriers)
    if (halfsel) {
        #pragma unroll
        for (int k = 0; k < 44; ++k) xsh[pl][k] = acc[k];
    }
    __syncthreads();
    if (!halfsel) {
        #pragma unroll
        for (int k = 0; k < 44; ++k) acc[k] += xsh[pl][k];
        #pragma unroll
        for (int k = 8; k < 44; ++k) xsh[pl][k] = acc[k];   // half1 only needs sigma part
    }
    __syncthreads();
    if (halfsel) {
        #pragma unroll
        for (int k = 8; k < 44; ++k) acc[k] = xsh[pl][k];
    }

    // ---- loc output (half 0 only): softplus(conv1x1 + b_n), layout [B,1,H,8]
    if (!halfsel) {
        const float bn = b_n[0];
        float lv[F_];
        #pragma unroll
        for (int w = 0; w < F_; ++w) lv[w] = softplus_f(acc[w] + bn);
        float* lo = out + (size_t)t * F_;
        *(float4*)(lo)     = make_float4(lv[0], lv[1], lv[2], lv[3]);
        *(float4*)(lo + 4) = make_float4(lv[4], lv[5], lv[6], lv[7]);
    }

    // ---- build symmetric A (upper triangle only) from sigma
    float A[F_][F_];
    {
        float sig[36];
        #pragma unroll
        for (int o = 0; o < OUT_CH; ++o) {
            const float bp = b_p[o];
            #pragma unroll
            for (int wo = 0; wo < 4; ++wo)
                sig[o * 4 + wo] = softplus_f(acc[8 + o * 4 + wo] + bp);
        }
        int k = 0;
        #pragma unroll
        for (int i = 0; i < F_; ++i)
            #pragma unroll
            for (int j = i; j < F_; ++j) {
                A[i][j] = sig[k];
                ++k;
            }
    }

    // Row-split V: this half tracks rows [myBase, myBase+4) only.
    const int myBase = halfsel << 2;
    float Vh[4][F_];
    #pragma unroll
    for (int i = 0; i < 4; ++i)
        #pragma unroll
        for (int j = 0; j < F_; ++j)
            Vh[i][j] = (myBase + i == j) ? 1.0f : 0.0f;

    // ---- parallel-ordering Jacobi; angle setup uses raw v_rcp/v_sqrt/v_rsq
    //      (1-2 ulp, fine vs the harness tolerance)
    for (int sweep = 0; sweep < NSWEEP; ++sweep) {
        #pragma unroll
        for (int r = 0; r < 7; ++r) {
            float cs[4], sn[4], tv[4];
            #pragma unroll
            for (int j = 0; j < 4; ++j) {
                const int p = PAIRS[r][j][0], q = PAIRS[r][j][1];
                const float apq = A[p][q];
                const float app = A[p][p];
                const float aqq = A[q][q];
                const float th = (aqq - app) * 0.5f * __builtin_amdgcn_rcpf(apq);
                float tt = __builtin_amdgcn_rcpf(fabsf(th) +
                              __builtin_amdgcn_sqrtf(fmaf(th, th, 1.0f)));
                tt = (th < 0.0f) ? -tt : tt;
                tt = (apq == 0.0f) ? 0.0f : tt;   // kills NaN from 0 * inf
                const float cc = __builtin_amdgcn_rsqf(fmaf(tt, tt, 1.0f));
                cs[j] = cc; sn[j] = tt * cc; tv[j] = tt;
            }
            // A updates: disjoint pairs -> sequential application == R A R^T
            #pragma unroll
            for (int j = 0; j < 4; ++j) {
                const int p = PAIRS[r][j][0], q = PAIRS[r][j][1];
                const float cc = cs[j], ss = sn[j], tt = tv[j];
                const float apq = A[p][q];
                A[p][p] = fmaf(-tt, apq, A[p][p]);
                A[q][q] = fmaf( tt, apq, A[q][q]);
                A[p][q] = 0.0f;
                #pragma unroll
                for (int i = 0; i < F_; ++i) {
                    if (i == p || i == q) continue;
                    const float aip = SYM(i, p);
                    const float aiq = SYM(i, q);
                    SYM(i, p) = fmaf(-ss, aiq, cc * aip);
                    SYM(i, q) = fmaf( ss, aip, cc * aiq);
                }
            }
            // V updates: only our 4 rows (column rotations stay within a row)
            #pragma unroll
            for (int j = 0; j < 4; ++j) {
                const int p = PAIRS[r][j][0], q = PAIRS[r][j][1];
                const float cc = cs[j], ss = sn[j];
                #pragma unroll
                for (int i = 0; i < 4; ++i) {
                    const float u = Vh[i][p], v = Vh[i][q];
                    Vh[i][p] = fmaf(-ss, v, cc * u);
                    Vh[i][q] = fmaf( ss, u, cc * v);
                }
            }
        }
    }

    // ---- eigenvalues (identical in both halves: same A, same rotations)
    float lam[F_];
    #pragma unroll
    for (int k = 0; k < F_; ++k) lam[k] = fmaxf(A[k][k], MIN_VEC);

    // ---- exchange V halves through LDS (reuse xsh; row has 65 >= 64 floats)
    __syncthreads();   // guard: half1's sigma reads above must complete
    {
        const int moff = myBase << 3;          // halfsel*32
        #pragma unroll
        for (int i = 0; i < 4; ++i)
            #pragma unroll
            for (int j = 0; j < F_; ++j)
                xsh[pl][moff + (i << 3) + j] = Vh[i][j];
    }
    __syncthreads();
    float Vo[4][F_];
    {
        const int ooff = (myBase ^ 4) << 3;    // other half's 32 floats
        #pragma unroll
        for (int i = 0; i < 4; ++i)
            #pragma unroll
            for (int j = 0; j < F_; ++j)
                Vo[i][j] = xsh[pl][ooff + (i << 3) + j];
    }

    // ---- reconstruct our 4 rows of PD = V * max(diag(A),MIN_VEC) * V^T.
    // Both halves use the same lam and same k-order -> output exactly symmetric.
    float W[4][F_];
    #pragma unroll
    for (int i = 0; i < 4; ++i)
        #pragma unroll
        for (int k = 0; k < F_; ++k)
            W[i][k] = Vh[i][k] * lam[k];

    float* po = out + LOC_N + (size_t)t * (F_ * F_) + myBase * F_;
    #pragma unroll
    for (int r = 0; r < 4; ++r) {
        float pa[4], pb[4];
        #pragma unroll
        for (int s = 0; s < 4; ++s) {
            float a0 = 0.0f, b0 = 0.0f;
            #pragma unroll
            for (int k = 0; k < F_; ++k) {
                a0 = fmaf(W[r][k], Vh[s][k], a0);   // columns in our half
                b0 = fmaf(W[r][k], Vo[s][k], b0);   // columns in other half
            }
            pa[s] = a0; pb[s] = b0;
        }
        float* pr = po + r * F_;
        *(float4*)(pr + myBase)       = make_float4(pa[0], pa[1], pa[2], pa[3]);
        *(float4*)(pr + (myBase ^ 4)) = make_float4(pb[0], pb[1], pb[2], pb[3]);
    }
}

extern "C" void kernel_launch(void* const* d_in, const int* in_sizes, int n_in,
                              void* d_out, int out_size, void* d_ws, size_t ws_size,
                              hipStream_t stream) {
    const float* x   = (const float*)d_in[0];
    const float* w_n = (const float*)d_in[1];
    const float* b_n = (const float*)d_in[2];
    const float* w_p = (const float*)d_in[3];
    const float* b_p = (const float*)d_in[4];
    float* out = (float*)d_out;

    dim3 grid(BH / 128);   // 1024 blocks, 2 threads per problem
    dim3 block(256);
    hipLaunchKernelGGL(mgauss_fused, grid, block, 0, stream,
                       x, w_n, b_n, w_p, b_p, out);
}